// Round 8
// baseline (484.372 us; speedup 1.0000x reference)
//
#include <hip/hip_runtime.h>
#include <float.h>

// N=65536 vectors (16x4096), D=64, K=1024, all fp32.
// d_out (f32 flat concat): quantized[N*D], one-hot[N*K], loss, cb_loss, commit_loss.
//
// Single fused main kernel:
//   1) bf16-split MFMA screen (hh+hl+lh, dot err <= ~5e-6) with per-row
//      (best, 2nd) tracking. gap >= BAND=6e-5 > 2*eta_np(1.6e-5) + 2*eps
//      certifies the np-f32 argmin.
//   2) uncertain rows (avg ~1.7/block) re-scanned IN-BLOCK with the
//      R4-verified bit-exact np-f32 replica (fp64 dot rounded once, numpy
//      pairwise tree for sx, strict < ascending k).
//   3) epilogue writes quantized/one-hot/loss ONCE with final indices.
#define NVEC 65536
#define KCB  1024
#define DIM  64
#define ENC_OFF   ((size_t)NVEC * DIM)
#define LOSS_OFF  (ENC_OFF + (size_t)NVEC * KCB)
#define BAND 6e-5f

// ws (bytes): [64..4160) float se[1024]; [8192..139264) eh; [139264..270336) el
#define WS_SE_BOFF 64
#define WS_EH_BOFF 8192
#define WS_EL_BOFF (8192 + 131072)

typedef __attribute__((ext_vector_type(8))) short short8;
typedef __attribute__((ext_vector_type(4))) float f32x4;
typedef __attribute__((ext_vector_type(4))) unsigned int u32x4;

__device__ __forceinline__ unsigned short f2bf(float f) {
    unsigned u = __float_as_uint(f);
    return (unsigned short)((u + 0x7FFFu + ((u >> 16) & 1u)) >> 16);  // RNE
}
__device__ __forceinline__ float bf2f(unsigned short h) {
    return __uint_as_float((unsigned)h << 16);
}

// prep: loss zero, np-path se[k] (fp64-exact -> fl32), bf16 hi/lo codebook split
__global__ __launch_bounds__(256) void vq_prep(const float* __restrict__ emb,
                                               float* __restrict__ se,
                                               unsigned short* __restrict__ eh,
                                               unsigned short* __restrict__ el,
                                               float* __restrict__ loss3) {
    int g = blockIdx.x * 256 + threadIdx.x;  // 16384 threads
    if (g < 3) loss3[g] = 0.0f;
    if (g < KCB) {
        const f32x4* er = (const f32x4*)(emb + (size_t)g * DIM);
        double s0 = 0.0, s1 = 0.0, s2 = 0.0, s3 = 0.0;  // verbatim R4 chains
#pragma unroll
        for (int i = 0; i < 16; i++) {
            f32x4 e = er[i];
            s0 = fma((double)e.x, (double)e.x, s0);
            s1 = fma((double)e.y, (double)e.y, s1);
            s2 = fma((double)e.z, (double)e.z, s2);
            s3 = fma((double)e.w, (double)e.w, s3);
        }
        se[g] = (float)((s0 + s1) + (s2 + s3));
    }
    for (int i = g; i < KCB * DIM; i += 64 * 256) {
        float v = emb[i];
        unsigned short h = f2bf(v);
        eh[i] = h;
        el[i] = f2bf(v - bf2f(h));
    }
}

// Fused main: block = 64 vectors (4 waves x 16 rows), all K=1024 codes.
// b-frags read directly from L2 (eh/el = 256 KB total, no LDS staging).
// MFMA 16x16x32 bf16, layouts verified end-to-end in R7:
//   A[m=lane&15][k=quad*8+j], B[k=quad*8+j][n=lane&15],
//   D col=lane&15 (code), rows = quad*4+reg (vectors).
__global__ __launch_bounds__(256) void vq_main(const float* __restrict__ x,
                                               const float* __restrict__ emb,
                                               const float* __restrict__ se,
                                               const unsigned short* __restrict__ eh,
                                               const unsigned short* __restrict__ el,
                                               float* __restrict__ outq,
                                               float* __restrict__ enc,
                                               float* __restrict__ lossacc) {
    __shared__ float sse[KCB];       // 4 KB
    __shared__ int   sidx[64];
    __shared__ int   sflag[64];
    __shared__ int   scnt;
    __shared__ float red[4];
    __shared__ float sxrow[4][64];   // per-wave refine x buffer

    const int tid = threadIdx.x;
    const int wave = tid >> 6, lane = tid & 63;
    const int q = lane >> 4, c = lane & 15;

    if (tid == 0) scnt = 0;
    for (int t = tid; t < KCB; t += 256) sse[t] = se[t];

    // A-frags: wave's 16 vectors, row m = c, k-chunks q*8+j and 32+q*8+j
    const int vecm = blockIdx.x * 64 + wave * 16 + c;
    float xa[16];
    {
        const f32x4* xp = (const f32x4*)(x + (size_t)vecm * DIM);
        ((f32x4*)xa)[0] = xp[2 * q];
        ((f32x4*)xa)[1] = xp[2 * q + 1];
        ((f32x4*)xa)[2] = xp[8 + 2 * q];
        ((f32x4*)xa)[3] = xp[8 + 2 * q + 1];
    }
    short8 ah0, al0, ah1, al1;
#pragma unroll
    for (int j = 0; j < 8; j++) {
        unsigned short h0 = f2bf(xa[j]);
        ah0[j] = (short)h0;
        al0[j] = (short)f2bf(xa[j] - bf2f(h0));
        unsigned short h1 = f2bf(xa[8 + j]);
        ah1[j] = (short)h1;
        al1[j] = (short)f2bf(xa[8 + j] - bf2f(h1));
    }
    __syncthreads();  // sse + scnt ready

    float b1[4], b2[4];
    int i1[4];
#pragma unroll
    for (int r = 0; r < 4; r++) { b1[r] = FLT_MAX; b2[r] = FLT_MAX; i1[r] = 0; }

#pragma unroll 2
    for (int t = 0; t < 64; t++) {  // 64 tiles x 16 codes
        int kcur = t * 16 + c;      // this lane's code column
        const unsigned short* bph = eh + ((size_t)kcur << 6) + q * 8;
        const unsigned short* bpl = el + ((size_t)kcur << 6) + q * 8;
        short8 bh0 = *(const short8*)bph;
        short8 bh1 = *(const short8*)(bph + 32);
        short8 bl0 = *(const short8*)bpl;
        short8 bl1 = *(const short8*)(bpl + 32);
        f32x4 acc = {0.f, 0.f, 0.f, 0.f};
        acc = __builtin_amdgcn_mfma_f32_16x16x32_bf16(ah0, bh0, acc, 0, 0, 0);
        acc = __builtin_amdgcn_mfma_f32_16x16x32_bf16(ah1, bh1, acc, 0, 0, 0);
        acc = __builtin_amdgcn_mfma_f32_16x16x32_bf16(ah0, bl0, acc, 0, 0, 0);
        acc = __builtin_amdgcn_mfma_f32_16x16x32_bf16(ah1, bl1, acc, 0, 0, 0);
        acc = __builtin_amdgcn_mfma_f32_16x16x32_bf16(al0, bh0, acc, 0, 0, 0);
        acc = __builtin_amdgcn_mfma_f32_16x16x32_bf16(al1, bh1, acc, 0, 0, 0);
        float sek = sse[kcur];
#pragma unroll
        for (int r = 0; r < 4; r++) {
            float v = fmaf(-2.f, acc[r], sek);
            bool lt = v < b1[r];
            b2[r] = fminf(fmaxf(v, b1[r]), b2[r]);  // keep 2nd-best
            b1[r] = lt ? v : b1[r];
            i1[r] = lt ? kcur : i1[r];
        }
    }

    // butterfly (b1,i1,b2) across the 16 lanes of each quad
#pragma unroll
    for (int m = 1; m <= 8; m <<= 1) {
#pragma unroll
        for (int r = 0; r < 4; r++) {
            float ob1 = __shfl_xor(b1[r], m, 64);
            float ob2 = __shfl_xor(b2[r], m, 64);
            int oi = __shfl_xor(i1[r], m, 64);
            float nb2 = fminf(fmaxf(b1[r], ob1), fminf(b2[r], ob2));
            if (ob1 < b1[r]) { b1[r] = ob1; i1[r] = oi; }
            b2[r] = nb2;
        }
    }
    if (c == 0) {
#pragma unroll
        for (int r = 0; r < 4; r++) {
            int row = wave * 16 + q * 4 + r;  // D rows = quad*4+reg
            sidx[row] = i1[r];
            if (b2[r] - b1[r] < BAND) {
                int p = atomicAdd(&scnt, 1);  // LDS atomic
                sflag[p] = row;
            }
        }
    }
    __syncthreads();

    // in-block refine of flagged rows: verbatim R4 bit-exact np replica
    int cnt = scnt;
    for (int f = wave; f < cnt; f += 4) {
        int row = sflag[f];
        int n = blockIdx.x * 64 + row;
        if (lane < 16)
            ((f32x4*)sxrow[wave])[lane] = ((const f32x4*)(x + (size_t)n * DIM))[lane];
        const float* xr = sxrow[wave];  // wave-internal LDS order via lgkmcnt

        // sx = numpy pairwise tree (8 strided chains + fixed combine); exact:
        // r starts at +0.0 so the b=0 add is exact.
        float r8[8];
#pragma unroll
        for (int j = 0; j < 8; j++) r8[j] = 0.0f;
#pragma unroll
        for (int b = 0; b < 8; b++)
#pragma unroll
            for (int j = 0; j < 8; j++)
                r8[j] = __fadd_rn(r8[j], __fmul_rn(xr[8 * b + j], xr[8 * b + j]));
        float sx = __fadd_rn(
            __fadd_rn(__fadd_rn(r8[0], r8[1]), __fadd_rn(r8[2], r8[3])),
            __fadd_rn(__fadd_rn(r8[4], r8[5]), __fadd_rn(r8[6], r8[7])));

        float bd = FLT_MAX;
        int bk = lane * 16;
        for (int cc = 0; cc < 16; cc++) {
            int k = lane * 16 + cc;  // ascending within lane
            const f32x4* er = (const f32x4*)(emb + (size_t)k * DIM);
            double s0 = 0.0, s1 = 0.0, s2 = 0.0, s3 = 0.0;  // verbatim R4
#pragma unroll
            for (int i = 0; i < 16; i++) {
                f32x4 e = er[i];
                f32x4 xv = ((const f32x4*)xr)[i];
                s0 = fma((double)e.x, (double)xv.x, s0);
                s1 = fma((double)e.y, (double)xv.y, s1);
                s2 = fma((double)e.z, (double)xv.z, s2);
                s3 = fma((double)e.w, (double)xv.w, s3);
            }
            float dot32 = (float)((s0 + s1) + (s2 + s3));
            float t1 = __fadd_rn(sx, sse[k]);
            float d = __fsub_rn(t1, __fmul_rn(2.0f, dot32));
            if (d < bd) { bd = d; bk = k; }  // strict <
        }
        // lexicographic (d,k) reduce = np first-index tie-break
        for (int off = 32; off; off >>= 1) {
            float od = __shfl_down(bd, off);
            int ok = __shfl_down(bk, off);
            if (od < bd || (od == bd && ok < bk)) { bd = od; bk = ok; }
        }
        if (lane == 0) sidx[row] = bk;
    }
    __syncthreads();  // final indices published

    // epilogue: quantized + loss with FINAL indices, then one-hot slab
    {
        int vec = tid >> 2, ch = tid & 3;
        int id = sidx[vec];
        const f32x4* ebp = (const f32x4*)(emb + (size_t)id * DIM) + ch * 4;
        const f32x4* xp = (const f32x4*)(x + (size_t)(blockIdx.x * 64 + vec) * DIM) + ch * 4;
        f32x4* op = (f32x4*)(outq + (size_t)(blockIdx.x * 64 + vec) * DIM) + ch * 4;
        float sq = 0.0f;
#pragma unroll
        for (int i = 0; i < 4; i++) {
            f32x4 e = ebp[i];
            f32x4 xv = xp[i];
            f32x4 d = e - xv;
            sq += d.x * d.x + d.y * d.y + d.z * d.z + d.w * d.w;
            __builtin_nontemporal_store(e, op + i);
        }
        for (int off = 32; off; off >>= 1) sq += __shfl_down(sq, off);
        if ((tid & 63) == 0) red[tid >> 6] = sq;
        __syncthreads();
        if (tid == 0) atomicAdd(lossacc, red[0] + red[1] + red[2] + red[3]);
    }

    f32x4* encb = (f32x4*)enc + (size_t)blockIdx.x * 64 * 256;
    for (int t = tid; t < 64 * 256; t += 256) {
        int id = sidx[t >> 8];
        int j = (t & 255) << 2;
        f32x4 v;
        v.x = (id == j + 0) ? 1.0f : 0.0f;
        v.y = (id == j + 1) ? 1.0f : 0.0f;
        v.z = (id == j + 2) ? 1.0f : 0.0f;
        v.w = (id == j + 3) ? 1.0f : 0.0f;
        __builtin_nontemporal_store(v, encb + t);
    }
}

__global__ void vq_fin(float* __restrict__ loss3) {
    if (threadIdx.x == 0 && blockIdx.x == 0) {
        float m = loss3[1] * (1.0f / (float)((size_t)NVEC * DIM));
        loss3[0] = 1.25f * m;  // loss = cb + 0.25*commit (values identical)
        loss3[1] = m;
        loss3[2] = m;
    }
}

extern "C" void kernel_launch(void* const* d_in, const int* in_sizes, int n_in,
                              void* d_out, int out_size, void* d_ws, size_t ws_size,
                              hipStream_t stream) {
    const float* x = (const float*)d_in[0];
    const float* emb = (const float*)d_in[1];
    float* out = (float*)d_out;
    float* se = (float*)((char*)d_ws + WS_SE_BOFF);
    unsigned short* eh = (unsigned short*)((char*)d_ws + WS_EH_BOFF);
    unsigned short* el = (unsigned short*)((char*)d_ws + WS_EL_BOFF);

    hipLaunchKernelGGL(vq_prep, dim3(64), dim3(256), 0, stream,
                       emb, se, eh, el, out + LOSS_OFF);
    hipLaunchKernelGGL(vq_main, dim3(NVEC / 64), dim3(256), 0, stream,
                       x, emb, se, eh, el, out, out + ENC_OFF, out + LOSS_OFF + 1);
    hipLaunchKernelGGL(vq_fin, dim3(1), dim3(64), 0, stream, out + LOSS_OFF);
}